// Round 1
// baseline (586.381 us; speedup 1.0000x reference)
//
#include <hip/hip_runtime.h>

// ConvTwist: grouped 3x3 conv, 64 groups of 8 in / 8 out channels.
// Output group i reads input group j = (i%4==0) ? i+3 : i-1.
// x: (32, 512, 56, 56) f32; W: (512, 8, 3, 3) f32; out: (32, 512, 56, 56) f32.

#define ROWS 8         // output rows per block
#define LROWS (ROWS + 2)
#define LSTRIDE 60     // padded LDS row: cols -1..58 (col c at index c+1)
#define BLOCK 448      // 8 ao * 14 xq * 4 ysub

__global__ __launch_bounds__(BLOCK)
void convtwist_kernel(const float* __restrict__ x,
                      const float* __restrict__ W,
                      float* __restrict__ out)
{
    __shared__ __align__(16) float s_in[8 * LROWS * LSTRIDE]; // 19.2 KB
    __shared__ float s_w[576];                                 // 8ao x 8bi x 9

    const int ytile = blockIdx.x;   // 0..6
    const int grp   = blockIdx.y;   // 0..63
    const int batch = blockIdx.z;   // 0..31

    const int jgrp = ((grp & 3) == 0) ? (grp + 3) : (grp - 1);
    const int y0 = ytile * ROWS;
    const int tid = threadIdx.x;

    // ---- stage weights for this group (8 out-ch x 72) ----
    const float* Wg = W + grp * 576;
    for (int idx = tid; idx < 576; idx += BLOCK) s_w[idx] = Wg[idx];

    // ---- stage input tile: 8 ch x LROWS rows x LSTRIDE cols, zero-padded ----
    const float* xb = x + ((size_t)batch * 512 + (size_t)jgrp * 8) * 3136;
    for (int idx = tid; idx < 8 * LROWS * LSTRIDE; idx += BLOCK) {
        int c  = idx % LSTRIDE;       // 0..59 -> col c-1
        int rr = idx / LSTRIDE;
        int r  = rr % LROWS;          // 0..9  -> input row y0-1+r
        int bi = rr / LROWS;          // 0..7
        int yy = y0 - 1 + r;
        int xx = c - 1;
        float v = 0.f;
        if (yy >= 0 && yy < 56 && xx >= 0 && xx < 56)
            v = xb[bi * 3136 + yy * 56 + xx];
        s_in[idx] = v;
    }
    __syncthreads();

    // ---- thread mapping: lanes contiguous in xq for conflict-light LDS ----
    const int xq   = tid % 14;        // x-quad: cols x0..x0+3, x0 = 4*xq
    const int rest = tid / 14;
    const int ao   = rest & 7;        // out-channel within group
    const int ysub = rest >> 3;       // 0..3 ; rows ysub and ysub+4
    const int x0   = xq * 4;

    // ---- weights to registers (broadcast reads: same ao -> same addr) ----
    float wr[8][3][3];
    #pragma unroll
    for (int bi = 0; bi < 8; ++bi)
        #pragma unroll
        for (int ky = 0; ky < 3; ++ky)
            #pragma unroll
            for (int kx = 0; kx < 3; ++kx)
                wr[bi][ky][kx] = s_w[ao * 72 + bi * 9 + ky * 3 + kx];

    float* outp = out + ((size_t)batch * 512 + (size_t)grp * 8 + ao) * 3136;

    #pragma unroll
    for (int yy = 0; yy < 2; ++yy) {
        const int yi = ysub + yy * 4;   // output row y0+yi; needs LDS rows yi..yi+2
        float acc0 = 0.f, acc1 = 0.f, acc2 = 0.f, acc3 = 0.f;
        #pragma unroll
        for (int bi = 0; bi < 8; ++bi) {
            const float* rowb = s_in + (bi * LROWS + yi) * LSTRIDE + x0;
            #pragma unroll
            for (int ky = 0; ky < 3; ++ky) {
                const float* p = rowb + ky * LSTRIDE;
                float4 v0 = *(const float4*)p;        // cols x0-1 .. x0+2 (16B aligned)
                float2 v1 = *(const float2*)(p + 4);  // cols x0+3, x0+4
                const float w0 = wr[bi][ky][0];
                const float w1 = wr[bi][ky][1];
                const float w2 = wr[bi][ky][2];
                acc0 = fmaf(v0.x, w0, acc0); acc0 = fmaf(v0.y, w1, acc0); acc0 = fmaf(v0.z, w2, acc0);
                acc1 = fmaf(v0.y, w0, acc1); acc1 = fmaf(v0.z, w1, acc1); acc1 = fmaf(v0.w, w2, acc1);
                acc2 = fmaf(v0.z, w0, acc2); acc2 = fmaf(v0.w, w1, acc2); acc2 = fmaf(v1.x, w2, acc2);
                acc3 = fmaf(v0.w, w0, acc3); acc3 = fmaf(v1.x, w1, acc3); acc3 = fmaf(v1.y, w2, acc3);
            }
        }
        float4 r = make_float4(acc0, acc1, acc2, acc3);
        *(float4*)(outp + (size_t)(y0 + yi) * 56 + x0) = r;
    }
}

extern "C" void kernel_launch(void* const* d_in, const int* in_sizes, int n_in,
                              void* d_out, int out_size, void* d_ws, size_t ws_size,
                              hipStream_t stream) {
    const float* x = (const float*)d_in[0];   // (32,512,56,56)
    const float* W = (const float*)d_in[1];   // (512,8,3,3)
    float* out = (float*)d_out;               // (32,512,56,56)

    dim3 grid(7, 64, 32);   // ytiles, groups, batch
    dim3 block(BLOCK);
    convtwist_kernel<<<grid, block, 0, stream>>>(x, W, out);
}

// Round 3
// 521.482 us; speedup vs baseline: 1.1244x; 1.1244x over previous
//
#include <hip/hip_runtime.h>

// ConvTwist: grouped 3x3 conv, 64 groups of 8 in / 8 out channels.
// Output group i reads input group j = (i%4==0) ? i+3 : i-1  (a bijection).
// x: (32, 512, 56, 56) f32; W: (512, 8, 3, 3) f32; out: (32, 512, 56, 56) f32.
//
// Block = (half-image, group, batch): 28 output rows of one (batch,group).
// LDS: 8 in-ch x 30 rows x 60 cols (col c at index c+1, zero-padded) = 57.6 KB
//      -> 2 blocks/CU (115.2 KB + weights), 14 waves/CU.
// Threads: 448 = 8 ao (LOW bits: wave reads broadcast across ao) x 14 xq x 4 strips.
// Each thread: 7 output rows x 4 cols for one out-channel; each LDS input row is
// read ONCE (b128+b64) and feeds up to 3 accumulator rows (ky-reuse).

#define LSTRIDE 60
#define LROWS 30
#define CH 8
#define BLOCK 448

__global__ __launch_bounds__(BLOCK, 4)
void convtwist_kernel(const float* __restrict__ x,
                      const float* __restrict__ W,
                      float* __restrict__ out)
{
    __shared__ __align__(16) float s_in[CH * LROWS * LSTRIDE]; // 57.6 KB
    __shared__ float s_w[576];                                  // 8ao x 8bi x 9

    const int half  = blockIdx.x;   // 0..1 -> output rows 28h .. 28h+27
    const int grp   = blockIdx.y;   // 0..63
    const int batch = blockIdx.z;   // 0..31

    const int jgrp = ((grp & 3) == 0) ? (grp + 3) : (grp - 1);
    const int tid  = threadIdx.x;
    const int y0   = half * 28;

    // ---- weights: 576 floats ----
    const float* Wg = W + grp * 576;
    for (int i = tid; i < 576; i += BLOCK) s_w[i] = Wg[i];

    // ---- zero the column pads: per (ch,row) dwords 0, 57, 58, 59 ----
    for (int i = tid; i < CH * LROWS * 4; i += BLOCK) {
        int rr = i >> 2, p = i & 3;
        s_in[rr * LSTRIDE + ((p == 0) ? 0 : (56 + p))] = 0.f;
    }

    // ---- interior stage: stride-1 lanes (coalesced global, conflict-free LDS) ----
    const float* xb = x + ((size_t)batch * 512 + (size_t)jgrp * 8) * 3136;
    {
        int col = tid % 56;          // lanes consecutive in col
        int rc  = tid / 56;          // 0..7 ; rc = ch*30 + row
        int ch  = 0, row = rc;
        #pragma unroll 1
        for (; rc < CH * LROWS; rc += 8) {
            int iy = y0 - 1 + row;   // input row for LDS row `row`
            float v = 0.f;
            if (iy >= 0 && iy < 56) v = xb[ch * 3136 + iy * 56 + col];
            s_in[(ch * LROWS + row) * LSTRIDE + 1 + col] = v;
            row += 8;
            if (row >= LROWS) { row -= LROWS; ++ch; }
        }
    }
    __syncthreads();

    // ---- thread mapping: ao in low bits => wave-wide LDS broadcast over ao ----
    const int ao    = tid & 7;
    const int m     = tid >> 3;      // 0..55
    const int xq    = m % 14;
    const int strip = m / 14;        // 0..3, 7 output rows each
    const int x0    = 4 * xq;

    float acc[7][4];
    #pragma unroll
    for (int o = 0; o < 7; ++o)
        #pragma unroll
        for (int c = 0; c < 4; ++c) acc[o][c] = 0.f;

    const float* wbase = s_w + ao * 72;
    const float* sbase = s_in + strip * 7 * LSTRIDE + x0;  // 16B aligned

    #pragma unroll 1
    for (int bi = 0; bi < 8; ++bi) {
        float w[9];
        #pragma unroll
        for (int t = 0; t < 9; ++t) w[t] = wbase[bi * 9 + t];
        const float* p = sbase + bi * (LROWS * LSTRIDE);
        #pragma unroll
        for (int r = 0; r < 9; ++r) {           // 9 input rows, each read once
            float4 v0 = *(const float4*)(p + r * LSTRIDE);
            float2 v1 = *(const float2*)(p + r * LSTRIDE + 4);
            float v[6] = {v0.x, v0.y, v0.z, v0.w, v1.x, v1.y};
            #pragma unroll
            for (int ky = 0; ky < 3; ++ky) {
                int o = r - ky;                 // compile-time pruned
                if (o >= 0 && o < 7) {
                    #pragma unroll
                    for (int kx = 0; kx < 3; ++kx) {
                        float wv = w[ky * 3 + kx];
                        #pragma unroll
                        for (int c = 0; c < 4; ++c)
                            acc[o][c] = fmaf(v[c + kx], wv, acc[o][c]);
                    }
                }
            }
        }
    }

    // ---- store: 7 rows x float4, 16B aligned ----
    float* outp = out + ((size_t)batch * 512 + (size_t)grp * 8 + ao) * 3136;
    #pragma unroll
    for (int o = 0; o < 7; ++o) {
        int y = y0 + strip * 7 + o;
        *(float4*)(outp + (size_t)y * 56 + x0) =
            make_float4(acc[o][0], acc[o][1], acc[o][2], acc[o][3]);
    }
}

extern "C" void kernel_launch(void* const* d_in, const int* in_sizes, int n_in,
                              void* d_out, int out_size, void* d_ws, size_t ws_size,
                              hipStream_t stream) {
    const float* x = (const float*)d_in[0];   // (32,512,56,56)
    const float* W = (const float*)d_in[1];   // (512,8,3,3)
    float* out = (float*)d_out;               // (32,512,56,56)

    dim3 grid(2, 64, 32);   // halves, groups, batch
    dim3 block(BLOCK);
    convtwist_kernel<<<grid, block, 0, stream>>>(x, W, out);
}

// Round 4
// 378.547 us; speedup vs baseline: 1.5490x; 1.3776x over previous
//
#include <hip/hip_runtime.h>

// ConvTwist: grouped 3x3 conv, 64 groups of 8 in / 8 out channels.
// Output group i reads input group j = (i%4==0) ? i+3 : i-1  (a bijection).
// x: (32, 512, 56, 56) f32; W: (512, 8, 3, 3) f32; out: (32, 512, 56, 56) f32.
//
// Block = (half-image, group, batch): 28 output rows of one (batch,group).
// LDS: 8 in-ch x 30 rows x 60 cols (col c at index c+1, zero-padded) = 57.6 KB.
// Staging is load-all-then-write-all: 8 independent float4 global loads per
// thread hoisted into registers (ONE latency exposure, not 30 serialized).
// Threads: 448 = 8 ao (LOW bits: wave-wide LDS broadcast over ao) x 14 xq x 4 strips.
// Compute: each thread 7 rows x 4 cols, each LDS input row read once (ky-reuse).

#define LSTRIDE 60
#define LROWS 30
#define CH 8
#define BLOCK 448
#define NQUAD (CH * LROWS * 14)   // 3360 float4s of interior

__global__ __launch_bounds__(BLOCK, 4)
void convtwist_kernel(const float* __restrict__ x,
                      const float* __restrict__ W,
                      float* __restrict__ out)
{
    __shared__ __align__(16) float s_in[CH * LROWS * LSTRIDE]; // 57.6 KB
    __shared__ float s_w[576];                                  // 8ao x 8bi x 9

    const int half  = blockIdx.x;   // 0..1 -> output rows 28h .. 28h+27
    const int grp   = blockIdx.y;   // 0..63
    const int batch = blockIdx.z;   // 0..31

    const int jgrp = ((grp & 3) == 0) ? (grp + 3) : (grp - 1);
    const int tid  = threadIdx.x;
    const int y0   = half * 28;

    // ---- weights: 576 floats = 144 float4 ----
    if (tid < 144)
        *(float4*)&s_w[tid * 4] = *(const float4*)(W + grp * 576 + tid * 4);

    // ---- zero the column pads: per (ch,row) dwords 0, 57, 58, 59 ----
    for (int i = tid; i < CH * LROWS * 4; i += BLOCK) {
        int rr = i >> 2, p = i & 3;
        s_in[rr * LSTRIDE + ((p == 0) ? 0 : (56 + p))] = 0.f;
    }

    // ---- interior stage: 8 hoisted masked float4 loads, then LDS writes ----
    const float* xb = x + ((size_t)batch * 512 + (size_t)jgrp * 8) * 3136;
    float4 v[8];
    int   off[8];
    #pragma unroll
    for (int k = 0; k < 8; ++k) {
        int i = tid + k * BLOCK;                  // < 3584; valid if < 3360
        int quad = i % 14;                        // float4 index within row
        int rr   = i / 14;                        // ch*30 + row
        int row  = rr % 30;
        int ch   = rr / 30;
        int iy   = y0 - 1 + row;
        off[k]   = rr * LSTRIDE + 1 + 4 * quad;
        v[k] = make_float4(0.f, 0.f, 0.f, 0.f);
        if (i < NQUAD && iy >= 0 && iy < 56)
            v[k] = *(const float4*)(xb + ch * 3136 + iy * 56 + 4 * quad);
    }
    #pragma unroll
    for (int k = 0; k < 8; ++k) {
        int i = tid + k * BLOCK;
        if (i < NQUAD) {
            s_in[off[k] + 0] = v[k].x;
            s_in[off[k] + 1] = v[k].y;
            s_in[off[k] + 2] = v[k].z;
            s_in[off[k] + 3] = v[k].w;
        }
    }
    __syncthreads();

    // ---- thread mapping: ao in low bits => wave-wide LDS broadcast over ao ----
    const int ao    = tid & 7;
    const int m     = tid >> 3;      // 0..55
    const int xq    = m % 14;
    const int strip = m / 14;        // 0..3, 7 output rows each
    const int x0    = 4 * xq;

    float acc[7][4];
    #pragma unroll
    for (int o = 0; o < 7; ++o)
        #pragma unroll
        for (int c = 0; c < 4; ++c) acc[o][c] = 0.f;

    const float* wbase = s_w + ao * 72;
    const float* sbase = s_in + strip * 7 * LSTRIDE + x0;  // 16B aligned

    #pragma unroll 1
    for (int bi = 0; bi < 8; ++bi) {
        float w[9];
        #pragma unroll
        for (int t = 0; t < 9; ++t) w[t] = wbase[bi * 9 + t];
        const float* p = sbase + bi * (LROWS * LSTRIDE);
        #pragma unroll
        for (int r = 0; r < 9; ++r) {           // 9 input rows, each read once
            float4 v0 = *(const float4*)(p + r * LSTRIDE);
            float2 v1 = *(const float2*)(p + r * LSTRIDE + 4);
            float vv[6] = {v0.x, v0.y, v0.z, v0.w, v1.x, v1.y};
            #pragma unroll
            for (int ky = 0; ky < 3; ++ky) {
                int o = r - ky;                 // compile-time pruned
                if (o >= 0 && o < 7) {
                    #pragma unroll
                    for (int kx = 0; kx < 3; ++kx) {
                        float wv = w[ky * 3 + kx];
                        #pragma unroll
                        for (int c = 0; c < 4; ++c)
                            acc[o][c] = fmaf(vv[c + kx], wv, acc[o][c]);
                    }
                }
            }
        }
    }

    // ---- store: 7 rows x float4, 16B aligned ----
    float* outp = out + ((size_t)batch * 512 + (size_t)grp * 8 + ao) * 3136;
    #pragma unroll
    for (int o = 0; o < 7; ++o) {
        int y = y0 + strip * 7 + o;
        *(float4*)(outp + (size_t)y * 56 + x0) =
            make_float4(acc[o][0], acc[o][1], acc[o][2], acc[o][3]);
    }
}

extern "C" void kernel_launch(void* const* d_in, const int* in_sizes, int n_in,
                              void* d_out, int out_size, void* d_ws, size_t ws_size,
                              hipStream_t stream) {
    const float* x = (const float*)d_in[0];   // (32,512,56,56)
    const float* W = (const float*)d_in[1];   // (512,8,3,3)
    float* out = (float*)d_out;               // (32,512,56,56)

    dim3 grid(2, 64, 32);   // halves, groups, batch
    dim3 block(BLOCK);
    convtwist_kernel<<<grid, block, 0, stream>>>(x, W, out);
}